// Round 5
// baseline (62.689 us; speedup 1.0000x reference)
//
#include <hip/hip_runtime.h>
#include <cmath>

// Problem constants (fixed by setup_inputs)
constexpr int B = 16, C = 3, H = 544, W = 960;
constexpr int OH = 136, OW = 240;
constexpr size_t HW = (size_t)H * W;

// ---------------- K1: gray + vertical 5-tap blur (streaming, no LDS) --------
// thread = (b, strip, quad): writes vtmp rows strip*16 .. strip*16+15 for
// cols quad*4 .. quad*4+3. Rolling 5-row window in registers.
constexpr int QPR = W / 4;         // 240 col-quads per row
constexpr int SROWS = 16;          // vtmp rows per thread
constexpr int NSTRIP = H / SROWS;  // 34
constexpr int NK1 = B * NSTRIP * QPR;  // 130560 = 510 * 256

__global__ __launch_bounds__(256)
void k1_vblur(const float* __restrict__ in, float* __restrict__ vtmp,
              float gn0, float gn1, float gn2)
{
    const int id = blockIdx.x * 256 + threadIdx.x;
    const int quad  = id % QPR;
    const int strip = (id / QPR) % NSTRIP;
    const int b     = id / (QPR * NSTRIP);
    const int r0 = strip * SROWS;
    const float* base = in + (size_t)b * C * HW + quad * 4;
    float* wbase = vtmp + (size_t)b * HW + quad * 4;

    auto loadgray = [&](int r) -> float4 {
        r = r < 0 ? -r : (r >= H ? 2 * H - 2 - r : r);
        const float* p = base + (size_t)r * W;
        const float4 rr = *reinterpret_cast<const float4*>(p);
        const float4 gg = *reinterpret_cast<const float4*>(p + HW);
        const float4 bb = *reinterpret_cast<const float4*>(p + 2 * HW);
        float4 g;
        g.x = fmaf(0.2989f, rr.x, fmaf(0.587f, gg.x, 0.114f * bb.x));
        g.y = fmaf(0.2989f, rr.y, fmaf(0.587f, gg.y, 0.114f * bb.y));
        g.z = fmaf(0.2989f, rr.z, fmaf(0.587f, gg.z, 0.114f * bb.z));
        g.w = fmaf(0.2989f, rr.w, fmaf(0.587f, gg.w, 0.114f * bb.w));
        return g;
    };

    float4 g[5];
    g[0] = loadgray(r0 - 2);
    g[1] = loadgray(r0 - 1);
    g[2] = loadgray(r0);
    g[3] = loadgray(r0 + 1);

    #pragma unroll
    for (int s = 0; s < SROWS; ++s) {
        g[(s + 4) % 5] = loadgray(r0 + 2 + s);
        const float4 a0 = g[s % 5],       a1 = g[(s + 1) % 5], a2 = g[(s + 2) % 5];
        const float4 a3 = g[(s + 3) % 5], a4 = g[(s + 4) % 5];
        float4 v;
        v.x = fmaf(gn0, a0.x + a4.x, fmaf(gn1, a1.x + a3.x, gn2 * a2.x));
        v.y = fmaf(gn0, a0.y + a4.y, fmaf(gn1, a1.y + a3.y, gn2 * a2.y));
        v.z = fmaf(gn0, a0.z + a4.z, fmaf(gn1, a1.z + a3.z, gn2 * a2.z));
        v.w = fmaf(gn0, a0.w + a4.w, fmaf(gn1, a1.w + a3.w, gn2 * a2.w));
        *reinterpret_cast<float4*>(wbase + (size_t)(r0 + s) * W) = v;
    }
}

// ---------------- K2: h-blur + sobel + pool + sigmoid (streaming) -----------
// thread = (b, ho, j0): computes out[b][ho][4*j0 .. 4*j0+3].
// Needs vtmp rows 4*ho-1 .. 4*ho+4, cols 16*j0-4 .. 16*j0+19 (6 float4/row).
constexpr int OQ = OW / 4;             // 60 out quads per row
constexpr int NK2 = B * OH * OQ;       // 130560 = 510 * 256

__global__ __launch_bounds__(256)
void k2_edge(const float* __restrict__ vtmp, float* __restrict__ out,
             float gn0, float gn1, float gn2)
{
    const int id = blockIdx.x * 256 + threadIdx.x;
    const int j0 = id % OQ;
    const int ho = (id / OQ) % OH;
    const int b  = id / (OQ * OH);
    const int c0 = 16 * j0 - 4;            // first loaded col
    const float* vb = vtmp + (size_t)b * HW;

    // v[i][0..23]: vtmp row s=4*ho-1+i, cols c0..c0+23 (row clamped; invalid
    // rows produce garbage that is zero-masked in smooth below).
    float v[6][24];
    const bool edge = (j0 == 0) || (j0 == OQ - 1);
    #pragma unroll
    for (int i = 0; i < 6; ++i) {
        int s = 4 * ho - 1 + i;
        const int sc = s < 0 ? 0 : (s >= H ? H - 1 : s);
        const float* p = vb + (size_t)sc * W;
        if (!edge) {
            #pragma unroll
            for (int q = 0; q < 6; ++q) {
                const float4 t = *reinterpret_cast<const float4*>(p + c0 + 4 * q);
                v[i][4 * q + 0] = t.x; v[i][4 * q + 1] = t.y;
                v[i][4 * q + 2] = t.z; v[i][4 * q + 3] = t.w;
            }
        } else {
            #pragma unroll
            for (int k = 0; k < 24; ++k) {
                int c = c0 + k;
                c = c < 0 ? -c : (c >= W ? 2 * W - 2 - c : c);  // reflect (h-blur)
                v[i][k] = p[c];
            }
        }
    }

    // smooth[i][k]: smooth row s=4*ho-1+i, col c=16*j0-1+k, k=0..17.
    // zero outside image (sobel zero-padding).
    const float rmask0 = (ho == 0) ? 0.f : 1.f;        // s=-1 row
    const float rmask5 = (ho == OH - 1) ? 0.f : 1.f;   // s=H row
    const float cmask0  = (j0 == 0) ? 0.f : 1.f;       // c=-1 col
    const float cmask17 = (j0 == OQ - 1) ? 0.f : 1.f;  // c=W col
    float sm[6][18];
    #pragma unroll
    for (int i = 0; i < 6; ++i) {
        const float rm = (i == 0) ? rmask0 : (i == 5 ? rmask5 : 1.f);
        #pragma unroll
        for (int k = 0; k < 18; ++k) {
            float s5 = fmaf(gn0, v[i][k + 1] + v[i][k + 5],
                       fmaf(gn1, v[i][k + 2] + v[i][k + 4], gn2 * v[i][k + 3]));
            const float cm = (k == 0) ? cmask0 : (k == 17 ? cmask17 : 1.f);
            sm[i][k] = s5 * rm * cm;
        }
    }

    // sobel + mag + 4x4 pool + sigmoid^2 for 4 output pixels
    float4 o;
    float* op = &o.x;
    #pragma unroll
    for (int jj = 0; jj < 4; ++jj) {
        float acc = 0.f;
        #pragma unroll
        for (int a = 0; a < 4; ++a) {        // mag row offset
            #pragma unroll
            for (int m = 0; m < 4; ++m) {    // mag col within pool
                const int k = 4 * jj + m;    // smooth col idx of (c-1)
                const float a00 = sm[a][k],     a01 = sm[a][k + 1],     a02 = sm[a][k + 2];
                const float a10 = sm[a + 1][k],                         a12 = sm[a + 1][k + 2];
                const float a20 = sm[a + 2][k], a21 = sm[a + 2][k + 1], a22 = sm[a + 2][k + 2];
                const float gx = (a02 - a00) + 2.f * (a12 - a10) + (a22 - a20);
                const float gy = (a20 + 2.f * a21 + a22) - (a00 + 2.f * a01 + a02);
                acc += sqrtf(gx * gx + gy * gy + 1e-6f);
            }
        }
        const float down = acc * (1.f / 16.f);
        const float x = 5.0f * (down - 0.2f);
        const float sg = 1.f / (1.f + expf(-x));
        op[jj] = sg * sg;
    }
    *reinterpret_cast<float4*>(out + (size_t)id * 4) = o;
}

// ---------------- fallback fused kernel (R4) if ws too small ----------------
constexpr int TOH = 8, TOW = 30, NTH = 17, NTW = 8, MH = 32, MW = 120;
constexpr int TR = 38, TS = 124, TC4 = 31, NTASK = TR * TC4;

__global__ __launch_bounds__(256, 6)
void edge_fused(const float* __restrict__ in, float* __restrict__ out,
                float gn0, float gn1, float gn2)
{
    __shared__ float tmp[TR * TS];
    const int tid = threadIdx.x;
    const int blk = blockIdx.x;
    const int tw = blk % NTW;
    const int th = (blk / NTW) % NTH;
    const int b  = blk / (NTW * NTH);
    const int mh0 = th * MH, mw0 = tw * MW;
    const float* inb = in + (size_t)b * C * HW;

    for (int idx = tid; idx < NTASK; idx += 256) {
        const int r = idx / TC4;
        const int c = idx - r * TC4;
        int gr = mh0 - 3 + r;
        gr = gr < 0 ? -gr : (gr >= H ? 2 * H - 2 - gr : gr);
        const int gcb = mw0 - 4 + 4 * c;
        float g8[8];
        if (gcb >= 0 && gcb + 8 < W) {
            #pragma unroll
            for (int ch = 0; ch < 3; ++ch) {
                const float wc = (ch == 0) ? 0.2989f : (ch == 1 ? 0.587f : 0.114f);
                const float* p = inb + ch * HW + (size_t)gr * W + gcb;
                const float4 a  = *reinterpret_cast<const float4*>(p);
                const float4 b4 = *reinterpret_cast<const float4*>(p + 4);
                const float  s  = p[8];
                const float arr[8] = {a.y, a.z, a.w, b4.x, b4.y, b4.z, b4.w, s};
                #pragma unroll
                for (int m = 0; m < 8; ++m)
                    g8[m] = (ch == 0) ? wc * arr[m] : fmaf(wc, arr[m], g8[m]);
            }
        } else {
            #pragma unroll
            for (int m = 0; m < 8; ++m) {
                int gc = gcb + 1 + m;
                gc = gc < 0 ? -gc : (gc >= W ? 2 * W - 2 - gc : gc);
                const float* p = inb + (size_t)gr * W + gc;
                g8[m] = 0.2989f * p[0] + 0.587f * p[HW] + 0.114f * p[2 * HW];
            }
        }
        float4 t;
        t.x = gn0 * g8[0] + gn1 * g8[1] + gn2 * g8[2] + gn1 * g8[3] + gn0 * g8[4];
        t.y = gn0 * g8[1] + gn1 * g8[2] + gn2 * g8[3] + gn1 * g8[4] + gn0 * g8[5];
        t.z = gn0 * g8[2] + gn1 * g8[3] + gn2 * g8[4] + gn1 * g8[5] + gn0 * g8[6];
        t.w = gn0 * g8[3] + gn1 * g8[4] + gn2 * g8[5] + gn1 * g8[6] + gn0 * g8[7];
        *reinterpret_cast<float4*>(&tmp[r * TS + 4 * c]) = t;
    }
    __syncthreads();

    if (tid < TOH * TOW) {
        const int orow = tid / TOW;
        const int ocol = tid - orow * TOW;
        const int sr0 = orow * 4, tc0 = ocol * 4;
        float sm[6][6];
        #pragma unroll
        for (int i = 0; i < 6; ++i)
            #pragma unroll
            for (int j = 0; j < 6; ++j) sm[i][j] = 0.f;
        const float gk[5] = {gn0, gn1, gn2, gn1, gn0};
        #pragma unroll
        for (int tr = 0; tr < 10; ++tr) {
            const float* p = &tmp[(sr0 + tr) * TS + tc0];
            const float4 u = *reinterpret_cast<const float4*>(p);
            const float4 vv = *reinterpret_cast<const float4*>(p + 4);
            const float t6[6] = {u.x, u.y, u.z, u.w, vv.x, vv.y};
            #pragma unroll
            for (int i = 0; i < 6; ++i) {
                const int k = tr - i;
                if (k >= 0 && k < 5) {
                    #pragma unroll
                    for (int j = 0; j < 6; ++j)
                        sm[i][j] = fmaf(gk[k], t6[j], sm[i][j]);
                }
            }
        }
        #pragma unroll
        for (int i = 0; i < 6; ++i) {
            const int hh = mh0 - 1 + sr0 + i;
            const float rm = (hh >= 0 && hh < H) ? 1.f : 0.f;
            #pragma unroll
            for (int j = 0; j < 6; ++j) {
                const int ww = mw0 - 1 + tc0 + j;
                sm[i][j] *= rm * ((ww >= 0 && ww < W) ? 1.f : 0.f);
            }
        }
        float acc = 0.f;
        #pragma unroll
        for (int i = 0; i < 4; ++i)
            #pragma unroll
            for (int j = 0; j < 4; ++j) {
                const float a00 = sm[i][j],     a01 = sm[i][j + 1],     a02 = sm[i][j + 2];
                const float a10 = sm[i + 1][j],                         a12 = sm[i + 1][j + 2];
                const float a20 = sm[i + 2][j], a21 = sm[i + 2][j + 1], a22 = sm[i + 2][j + 2];
                const float gx = (a02 - a00) + 2.f * (a12 - a10) + (a22 - a20);
                const float gy = (a20 + 2.f * a21 + a22) - (a00 + 2.f * a01 + a02);
                acc += sqrtf(gx * gx + gy * gy + 1e-6f);
            }
        const float down = acc * (1.f / 16.f);
        const float x = 5.0f * (down - 0.2f);
        const float sg = 1.f / (1.f + expf(-x));
        const size_t o = ((size_t)b * OH + (th * TOH + orow)) * OW + (tw * TOW + ocol);
        out[o] = sg * sg;
    }
}

extern "C" void kernel_launch(void* const* d_in, const int* in_sizes, int n_in,
                              void* d_out, int out_size, void* d_ws, size_t ws_size,
                              hipStream_t stream) {
    const float* in = (const float*)d_in[0];
    float* out = (float*)d_out;

    const double g0 = std::exp(-4.0 / 4.5);
    const double g1 = std::exp(-1.0 / 4.5);
    const double g2 = 1.0;
    const double S = 2.0 * (g0 + g1) + g2;
    const float gn0 = (float)(g0 / S);
    const float gn1 = (float)(g1 / S);
    const float gn2 = (float)(g2 / S);

    const size_t need = (size_t)B * HW * sizeof(float);  // 33.4 MB
    if (ws_size >= need) {
        float* vtmp = (float*)d_ws;
        hipLaunchKernelGGL(k1_vblur, dim3(NK1 / 256), dim3(256), 0, stream,
                           in, vtmp, gn0, gn1, gn2);
        hipLaunchKernelGGL(k2_edge, dim3(NK2 / 256), dim3(256), 0, stream,
                           vtmp, out, gn0, gn1, gn2);
    } else {
        hipLaunchKernelGGL(edge_fused, dim3(B * NTH * NTW), dim3(256), 0, stream,
                           in, out, gn0, gn1, gn2);
    }
}

// Round 6
// 43.069 us; speedup vs baseline: 1.4556x; 1.4556x over previous
//
#include <hip/hip_runtime.h>
#include <cmath>

// Problem constants (fixed by setup_inputs)
constexpr int B = 16, C = 3, H = 544, W = 960;
constexpr int OH = 136, OW = 240;
constexpr size_t HW = (size_t)H * W;

constexpr int TOH = 8, TOW = 30, NTH = 17, NTW = 8, MH = 32, MW = 120;
constexpr int TR = 38;               // tmp rows
constexpr int TS = 124;              // tmp row stride (floats)
constexpr int TC4 = 31;              // float4 col-groups per row
constexpr int NTASK = TR * TC4;      // 1178

__global__ __launch_bounds__(256)
void edge_fused(const float* __restrict__ in, float* __restrict__ out,
                float gn0, float gn1, float gn2)
{
    __shared__ float tmp[TR * TS];   // 18848 B

    const int tid = threadIdx.x;
    const int blk = blockIdx.x;
    const int tw = blk % NTW;
    const int th = (blk / NTW) % NTH;
    const int b  = blk / (NTW * NTH);
    const int mh0 = th * MH, mw0 = tw * MW;
    const float* inb = in + (size_t)b * C * HW;

    // ---- stage A: gray + horizontal 5-tap blur, 2-deep software pipeline ----
    // task (r,c): tmp[r][4c..4c+3] from gray cols gcb+1..gcb+8, gcb=mw0-4+4c.
    auto taskaddr = [&](int idx, int& gr, int& gcb, bool& fast) {
        const int r = idx / TC4;
        const int c = idx - r * TC4;
        int g = mh0 - 3 + r;                        // row reflect
        g = g < 0 ? -g : (g >= H ? 2 * H - 2 - g : g);
        gr = g;
        gcb = mw0 - 4 + 4 * c;
        fast = (gcb >= 0) & (gcb + 8 < W);
    };

    int idx0 = tid;
    int gr0 = 0, gcb0 = 0;
    bool f0 = false;
    float4 A0[3], B0[3];
    float S0[3];
    if (idx0 < NTASK) {
        taskaddr(idx0, gr0, gcb0, f0);
        if (f0) {
            #pragma unroll
            for (int ch = 0; ch < 3; ++ch) {
                const float* p = inb + (size_t)ch * HW + (size_t)gr0 * W + gcb0;
                A0[ch] = *reinterpret_cast<const float4*>(p);
                B0[ch] = *reinterpret_cast<const float4*>(p + 4);
                S0[ch] = p[8];
            }
        }
    }

    while (idx0 < NTASK) {
        // prefetch task t+1 (independent of task t's consume)
        const int idx1 = idx0 + 256;
        int gr1 = 0, gcb1 = 0;
        bool f1 = false;
        float4 A1[3], B1[3];
        float S1[3];
        if (idx1 < NTASK) {
            taskaddr(idx1, gr1, gcb1, f1);
            if (f1) {
                #pragma unroll
                for (int ch = 0; ch < 3; ++ch) {
                    const float* p = inb + (size_t)ch * HW + (size_t)gr1 * W + gcb1;
                    A1[ch] = *reinterpret_cast<const float4*>(p);
                    B1[ch] = *reinterpret_cast<const float4*>(p + 4);
                    S1[ch] = p[8];
                }
            }
        }

        // consume task t
        float g8[8];
        if (f0) {
            #pragma unroll
            for (int ch = 0; ch < 3; ++ch) {
                const float wc = (ch == 0) ? 0.2989f : (ch == 1 ? 0.587f : 0.114f);
                const float arr[8] = {A0[ch].y, A0[ch].z, A0[ch].w, B0[ch].x,
                                      B0[ch].y, B0[ch].z, B0[ch].w, S0[ch]};
                #pragma unroll
                for (int m = 0; m < 8; ++m)
                    g8[m] = (ch == 0) ? wc * arr[m] : fmaf(wc, arr[m], g8[m]);
            }
        } else {
            // column-boundary tasks only: scalar loads with col reflect
            #pragma unroll
            for (int m = 0; m < 8; ++m) {
                int gc = gcb0 + 1 + m;
                gc = gc < 0 ? -gc : (gc >= W ? 2 * W - 2 - gc : gc);
                const float* p = inb + (size_t)gr0 * W + gc;
                g8[m] = 0.2989f * p[0] + 0.587f * p[HW] + 0.114f * p[2 * HW];
            }
        }
        const int r = idx0 / TC4;
        const int c = idx0 - r * TC4;
        float4 t;
        t.x = gn0 * g8[0] + gn1 * g8[1] + gn2 * g8[2] + gn1 * g8[3] + gn0 * g8[4];
        t.y = gn0 * g8[1] + gn1 * g8[2] + gn2 * g8[3] + gn1 * g8[4] + gn0 * g8[5];
        t.z = gn0 * g8[2] + gn1 * g8[3] + gn2 * g8[4] + gn1 * g8[5] + gn0 * g8[6];
        t.w = gn0 * g8[3] + gn1 * g8[4] + gn2 * g8[5] + gn1 * g8[6] + gn0 * g8[7];
        *reinterpret_cast<float4*>(&tmp[r * TS + 4 * c]) = t;

        // rotate pipeline
        idx0 = idx1; gr0 = gr1; gcb0 = gcb1; f0 = f1;
        #pragma unroll
        for (int ch = 0; ch < 3; ++ch) {
            A0[ch] = A1[ch]; B0[ch] = B1[ch]; S0[ch] = S1[ch];
        }
    }
    __syncthreads();

    // ---- stage B: vertical blur (registers) + sobel + pool + sigmoid ----
    if (tid < TOH * TOW) {
        const int orow = tid / TOW;
        const int ocol = tid - orow * TOW;
        const int sr0 = orow * 4, tc0 = ocol * 4;

        float sm[6][6];
        #pragma unroll
        for (int i = 0; i < 6; ++i)
            #pragma unroll
            for (int j = 0; j < 6; ++j) sm[i][j] = 0.f;

        const float gk[5] = {gn0, gn1, gn2, gn1, gn0};
        #pragma unroll
        for (int tr = 0; tr < 10; ++tr) {
            const float* p = &tmp[(sr0 + tr) * TS + tc0];
            const float4 u = *reinterpret_cast<const float4*>(p);
            const float4 vv = *reinterpret_cast<const float4*>(p + 4);
            const float t6[6] = {u.x, u.y, u.z, u.w, vv.x, vv.y};
            #pragma unroll
            for (int i = 0; i < 6; ++i) {
                const int k = tr - i;
                if (k >= 0 && k < 5) {
                    #pragma unroll
                    for (int j = 0; j < 6; ++j)
                        sm[i][j] = fmaf(gk[k], t6[j], sm[i][j]);
                }
            }
        }

        // sobel zero-padding: zero sm outside the image
        #pragma unroll
        for (int i = 0; i < 6; ++i) {
            const int hh = mh0 - 1 + sr0 + i;
            const float rm = (hh >= 0 && hh < H) ? 1.f : 0.f;
            #pragma unroll
            for (int j = 0; j < 6; ++j) {
                const int ww = mw0 - 1 + tc0 + j;
                sm[i][j] *= rm * ((ww >= 0 && ww < W) ? 1.f : 0.f);
            }
        }

        float acc = 0.f;
        #pragma unroll
        for (int i = 0; i < 4; ++i) {
            #pragma unroll
            for (int j = 0; j < 4; ++j) {
                const float a00 = sm[i][j],     a01 = sm[i][j + 1],     a02 = sm[i][j + 2];
                const float a10 = sm[i + 1][j],                         a12 = sm[i + 1][j + 2];
                const float a20 = sm[i + 2][j], a21 = sm[i + 2][j + 1], a22 = sm[i + 2][j + 2];
                const float gx = (a02 - a00) + 2.f * (a12 - a10) + (a22 - a20);
                const float gy = (a20 + 2.f * a21 + a22) - (a00 + 2.f * a01 + a02);
                acc += sqrtf(gx * gx + gy * gy + 1e-6f);
            }
        }
        const float down = acc * (1.f / 16.f);
        const float x = 5.0f * (down - 0.2f);
        const float sg = 1.f / (1.f + expf(-x));
        const size_t o = ((size_t)b * OH + (th * TOH + orow)) * OW + (tw * TOW + ocol);
        out[o] = sg * sg;
    }
}

extern "C" void kernel_launch(void* const* d_in, const int* in_sizes, int n_in,
                              void* d_out, int out_size, void* d_ws, size_t ws_size,
                              hipStream_t stream) {
    const float* in = (const float*)d_in[0];
    float* out = (float*)d_out;

    // Gaussian 1D coefficients (separable: outer(g,g)/(sum g)^2), exact in double.
    const double g0 = std::exp(-4.0 / 4.5);  // x=2
    const double g1 = std::exp(-1.0 / 4.5);  // x=1
    const double g2 = 1.0;                   // x=0
    const double S = 2.0 * (g0 + g1) + g2;
    const float gn0 = (float)(g0 / S);
    const float gn1 = (float)(g1 / S);
    const float gn2 = (float)(g2 / S);

    hipLaunchKernelGGL(edge_fused, dim3(B * NTH * NTW), dim3(256), 0, stream,
                       in, out, gn0, gn1, gn2);
}

// Round 7
// 36.125 us; speedup vs baseline: 1.7353x; 1.1922x over previous
//
#include <hip/hip_runtime.h>
#include <cmath>

// Problem constants (fixed by setup_inputs)
constexpr int B = 16, C = 3, H = 544, W = 960;
constexpr int OH = 136, OW = 240;
constexpr size_t HW = (size_t)H * W;

constexpr int TOH = 8, TOW = 30, NTH = 17, NTW = 8, MH = 32, MW = 120;
constexpr int TR = 40;     // tmp rows: gray rows mh0-4 .. mh0+35 (rows 0,39 unused pad)
constexpr int TS = 132;    // tmp row stride (floats, %4==0 for float4 alignment)
constexpr int TC4 = 32;    // quads per row -> 40*32 = 1280 tasks = 5 per thread
constexpr int NT = 5;      // tasks per thread (compile-time!)

__global__ __launch_bounds__(256)
void edge_fused(const float* __restrict__ in, float* __restrict__ out,
                float gn0, float gn1, float gn2)
{
    __shared__ float tmp[TR * TS];   // 21120 B

    const int tid = threadIdx.x;
    const int blk = blockIdx.x;
    const int tw = blk % NTW;
    const int th = (blk / NTW) % NTH;
    const int b  = blk / (NTW * NTH);
    const int mh0 = th * MH, mw0 = tw * MW;
    const float* inb = in + (size_t)b * C * HW;

    // ---- A1: gray + horizontal 5-tap blur. 5 tasks/thread, fully unrolled,
    //      ALL loads unconditional (cols clamped; border quads fixed in A2). ----
    float4 Aq[NT][3], Bq[NT][3];
    float  Sc[NT][3];
    #pragma unroll
    for (int k = 0; k < NT; ++k) {
        const int idx = tid + 256 * k;
        const int r = idx >> 5;          // /32
        const int c = idx & 31;
        int g = mh0 - 4 + r;             // row reflect (always valid)
        g = g < 0 ? -g : (g >= H ? 2 * H - 2 - g : g);
        int gcb = mw0 - 4 + 4 * c;       // col clamp (keeps 16B alignment)
        gcb = gcb < 0 ? 0 : (gcb > W - 12 ? W - 12 : gcb);
        const float* p = inb + (size_t)g * W + gcb;
        #pragma unroll
        for (int ch = 0; ch < 3; ++ch) {
            Aq[k][ch] = *reinterpret_cast<const float4*>(p);
            Bq[k][ch] = *reinterpret_cast<const float4*>(p + 4);
            Sc[k][ch] = p[8];
            p += HW;
        }
    }
    #pragma unroll
    for (int k = 0; k < NT; ++k) {
        const int idx = tid + 256 * k;
        const int r = idx >> 5;
        const int c = idx & 31;
        const float a0[8] = {Aq[k][0].y, Aq[k][0].z, Aq[k][0].w, Bq[k][0].x,
                             Bq[k][0].y, Bq[k][0].z, Bq[k][0].w, Sc[k][0]};
        const float a1[8] = {Aq[k][1].y, Aq[k][1].z, Aq[k][1].w, Bq[k][1].x,
                             Bq[k][1].y, Bq[k][1].z, Bq[k][1].w, Sc[k][1]};
        const float a2[8] = {Aq[k][2].y, Aq[k][2].z, Aq[k][2].w, Bq[k][2].x,
                             Bq[k][2].y, Bq[k][2].z, Bq[k][2].w, Sc[k][2]};
        float g8[8];
        #pragma unroll
        for (int m = 0; m < 8; ++m)
            g8[m] = fmaf(0.2989f, a0[m], fmaf(0.587f, a1[m], 0.114f * a2[m]));
        float4 t;
        t.x = gn0 * g8[0] + gn1 * g8[1] + gn2 * g8[2] + gn1 * g8[3] + gn0 * g8[4];
        t.y = gn0 * g8[1] + gn1 * g8[2] + gn2 * g8[3] + gn1 * g8[4] + gn0 * g8[5];
        t.z = gn0 * g8[2] + gn1 * g8[3] + gn2 * g8[4] + gn1 * g8[5] + gn0 * g8[6];
        t.w = gn0 * g8[3] + gn1 * g8[4] + gn2 * g8[5] + gn1 * g8[6] + gn0 * g8[7];
        *reinterpret_cast<float4*>(&tmp[r * TS + 4 * c]) = t;
    }
    __syncthreads();

    // ---- A2: fix border quads with true column reflect (block-uniform branch) ----
    if (tw == 0 || tw == NTW - 1) {
        const int ntask = (tw == 0) ? TR : 2 * TR;   // c=0 | c=29,30
        if (tid < ntask) {
            int r, c;
            if (tw == 0) { r = tid; c = 0; }
            else         { r = tid >> 1; c = 29 + (tid & 1); }
            int g = mh0 - 4 + r;
            g = g < 0 ? -g : (g >= H ? 2 * H - 2 - g : g);
            const int gcb = mw0 - 4 + 4 * c;
            float g8[8];
            #pragma unroll
            for (int m = 0; m < 8; ++m) {
                int gc = gcb + 1 + m;
                gc = gc < 0 ? -gc : (gc >= W ? 2 * W - 2 - gc : gc);
                const float* p = inb + (size_t)g * W + gc;
                g8[m] = 0.2989f * p[0] + 0.587f * p[HW] + 0.114f * p[2 * HW];
            }
            float4 t;
            t.x = gn0 * g8[0] + gn1 * g8[1] + gn2 * g8[2] + gn1 * g8[3] + gn0 * g8[4];
            t.y = gn0 * g8[1] + gn1 * g8[2] + gn2 * g8[3] + gn1 * g8[4] + gn0 * g8[5];
            t.z = gn0 * g8[2] + gn1 * g8[3] + gn2 * g8[4] + gn1 * g8[5] + gn0 * g8[6];
            t.w = gn0 * g8[3] + gn1 * g8[4] + gn2 * g8[5] + gn1 * g8[6] + gn0 * g8[7];
            *reinterpret_cast<float4*>(&tmp[r * TS + 4 * c]) = t;
        }
    }
    __syncthreads();

    // ---- stage B: vertical blur (regs) + sobel + pool + sigmoid ----
    if (tid < TOH * TOW) {
        const int orow = tid / TOW;
        const int ocol = tid - orow * TOW;
        const int sr0 = orow * 4, tc0 = ocol * 4;

        float sm[6][6];
        #pragma unroll
        for (int i = 0; i < 6; ++i)
            #pragma unroll
            for (int j = 0; j < 6; ++j) sm[i][j] = 0.f;

        const float gk[5] = {gn0, gn1, gn2, gn1, gn0};
        #pragma unroll
        for (int tr = 0; tr < 10; ++tr) {
            const float* p = &tmp[(sr0 + 1 + tr) * TS + tc0];  // +1: row-pad offset
            const float4 u  = *reinterpret_cast<const float4*>(p);
            const float4 vv = *reinterpret_cast<const float4*>(p + 4);
            const float t6[6] = {u.x, u.y, u.z, u.w, vv.x, vv.y};
            #pragma unroll
            for (int i = 0; i < 6; ++i) {
                const int k = tr - i;
                if (k >= 0 && k < 5) {
                    #pragma unroll
                    for (int j = 0; j < 6; ++j)
                        sm[i][j] = fmaf(gk[k], t6[j], sm[i][j]);
                }
            }
        }

        // sobel zero-padding: zero sm outside the image
        #pragma unroll
        for (int i = 0; i < 6; ++i) {
            const int hh = mh0 - 1 + sr0 + i;
            const float rm = (hh >= 0 && hh < H) ? 1.f : 0.f;
            #pragma unroll
            for (int j = 0; j < 6; ++j) {
                const int ww = mw0 - 1 + tc0 + j;
                sm[i][j] *= rm * ((ww >= 0 && ww < W) ? 1.f : 0.f);
            }
        }

        // 4 independent accumulators (break serial sqrt chain)
        float acc[4] = {0.f, 0.f, 0.f, 0.f};
        #pragma unroll
        for (int i = 0; i < 4; ++i) {
            #pragma unroll
            for (int j = 0; j < 4; ++j) {
                const float a00 = sm[i][j],     a01 = sm[i][j + 1],     a02 = sm[i][j + 2];
                const float a10 = sm[i + 1][j],                         a12 = sm[i + 1][j + 2];
                const float a20 = sm[i + 2][j], a21 = sm[i + 2][j + 1], a22 = sm[i + 2][j + 2];
                const float gx = (a02 - a00) + 2.f * (a12 - a10) + (a22 - a20);
                const float gy = (a20 + 2.f * a21 + a22) - (a00 + 2.f * a01 + a02);
                acc[i] += sqrtf(gx * gx + gy * gy + 1e-6f);
            }
        }
        const float down = ((acc[0] + acc[1]) + (acc[2] + acc[3])) * (1.f / 16.f);
        const float x = 5.0f * (down - 0.2f);
        const float sg = 1.f / (1.f + expf(-x));
        const size_t o = ((size_t)b * OH + (th * TOH + orow)) * OW + (tw * TOW + ocol);
        out[o] = sg * sg;
    }
}

extern "C" void kernel_launch(void* const* d_in, const int* in_sizes, int n_in,
                              void* d_out, int out_size, void* d_ws, size_t ws_size,
                              hipStream_t stream) {
    const float* in = (const float*)d_in[0];
    float* out = (float*)d_out;

    // Gaussian 1D coefficients (separable: outer(g,g)/(sum g)^2), exact in double.
    const double g0 = std::exp(-4.0 / 4.5);  // x=2
    const double g1 = std::exp(-1.0 / 4.5);  // x=1
    const double g2 = 1.0;                   // x=0
    const double S = 2.0 * (g0 + g1) + g2;
    const float gn0 = (float)(g0 / S);
    const float gn1 = (float)(g1 / S);
    const float gn2 = (float)(g2 / S);

    hipLaunchKernelGGL(edge_fused, dim3(B * NTH * NTW), dim3(256), 0, stream,
                       in, out, gn0, gn1, gn2);
}

// Round 8
// 33.983 us; speedup vs baseline: 1.8447x; 1.0631x over previous
//
#include <hip/hip_runtime.h>
#include <cmath>

// Problem constants (fixed by setup_inputs)
constexpr int B = 16, C = 3, H = 544, W = 960;
constexpr int OH = 136, OW = 240;
constexpr size_t HW = (size_t)H * W;

constexpr int TOH = 8, TOW = 30, NTH = 17, NTW = 8, MH = 32, MW = 120;
constexpr int GR = 40;     // gray rows: global rows mh0-4 .. mh0+35 (rows 0,39 pad)
constexpr int GS = 132;    // gray row stride (floats)
constexpr int NT = 5;      // tasks per thread: 40 rows x 32 quads = 1280 = 5*256

__global__ __launch_bounds__(256)
void edge_fused(const float* __restrict__ in, float* __restrict__ out,
                float gn0, float gn1, float gn2)
{
    __shared__ float gray[GR * GS];   // 21120 B

    const int tid = threadIdx.x;
    const int blk = blockIdx.x;
    const int tw = blk % NTW;
    const int th = (blk / NTW) % NTH;
    const int b  = blk / (NTW * NTH);
    const int mh0 = th * MH, mw0 = tw * MW;
    const float* inb = in + (size_t)b * C * HW;

    // ---- phase A: load unique RGB region once (batched, unconditional),
    //      convert to gray in LDS. gray[r][lc] <-> global (mh0-4+r, mw0-4+lc).
    float4 Rv[NT], Gv[NT], Bv[NT];
    #pragma unroll
    for (int k = 0; k < NT; ++k) {
        const int idx = tid + 256 * k;
        const int r = idx >> 5;          // /32 quads per row
        const int c = idx & 31;
        int g = mh0 - 4 + r;             // row reflect (always valid)
        g = g < 0 ? -g : (g >= H ? 2 * H - 2 - g : g);
        int gcb = mw0 - 4 + 4 * c;       // col clamp keeps alignment; edge quads fixed below
        gcb = gcb < 0 ? 0 : (gcb > W - 4 ? W - 4 : gcb);
        const float* p = inb + (size_t)g * W + gcb;
        Rv[k] = *reinterpret_cast<const float4*>(p);
        Gv[k] = *reinterpret_cast<const float4*>(p + HW);
        Bv[k] = *reinterpret_cast<const float4*>(p + 2 * HW);
    }
    #pragma unroll
    for (int k = 0; k < NT; ++k) {
        const int idx = tid + 256 * k;
        const int r = idx >> 5;
        const int c = idx & 31;
        float4 g;
        g.x = fmaf(0.2989f, Rv[k].x, fmaf(0.587f, Gv[k].x, 0.114f * Bv[k].x));
        g.y = fmaf(0.2989f, Rv[k].y, fmaf(0.587f, Gv[k].y, 0.114f * Bv[k].y));
        g.z = fmaf(0.2989f, Rv[k].z, fmaf(0.587f, Gv[k].z, 0.114f * Bv[k].z));
        g.w = fmaf(0.2989f, Rv[k].w, fmaf(0.587f, Gv[k].w, 0.114f * Bv[k].w));
        const bool edgeq = (tw == 0 && c == 0) || (tw == NTW - 1 && c == 31);
        if (!edgeq)
            *reinterpret_cast<float4*>(&gray[r * GS + 4 * c]) = g;
    }
    // column-reflect fixup for the 40 edge quads (only writer of those quads)
    if ((tw == 0 || tw == NTW - 1) && tid < GR) {
        const int r = tid;
        const int c = (tw == 0) ? 0 : 31;
        int g = mh0 - 4 + r;
        g = g < 0 ? -g : (g >= H ? 2 * H - 2 - g : g);
        float4 gv;
        float* gp = &gv.x;
        #pragma unroll
        for (int m = 0; m < 4; ++m) {
            int gc = mw0 - 4 + 4 * c + m;
            gc = gc < 0 ? -gc : (gc >= W ? 2 * W - 2 - gc : gc);
            const float* p = inb + (size_t)g * W + gc;
            gp[m] = 0.2989f * p[0] + 0.587f * p[HW] + 0.114f * p[2 * HW];
        }
        *reinterpret_cast<float4*>(&gray[r * GS + 4 * c]) = gv;
    }
    __syncthreads();

    // ---- phase B: rolling v-blur from LDS + in-register h-blur + sobel+pool ----
    if (tid < TOH * TOW) {
        const int orow = tid / TOW;
        const int ocol = tid - orow * TOW;
        const int lc0 = 4 * ocol;        // gray local col base (reads lc0..lc0+11)
        const int rb = 4 * orow + 1;     // gray local row base (reads rb..rb+9)

        float vb[6][12];                 // v-blurred gray, smooth rows i=0..5
        #pragma unroll
        for (int i = 0; i < 6; ++i)
            #pragma unroll
            for (int j = 0; j < 12; ++j) vb[i][j] = 0.f;

        const float gk[5] = {gn0, gn1, gn2, gn1, gn0};
        #pragma unroll
        for (int tr = 0; tr < 10; ++tr) {
            const float* p = &gray[(rb + tr) * GS + lc0];
            const float4 u = *reinterpret_cast<const float4*>(p);
            const float4 v = *reinterpret_cast<const float4*>(p + 4);
            const float4 w = *reinterpret_cast<const float4*>(p + 8);
            const float t12[12] = {u.x, u.y, u.z, u.w, v.x, v.y, v.z, v.w,
                                   w.x, w.y, w.z, w.w};
            #pragma unroll
            for (int i = 0; i < 6; ++i) {
                const int m = tr - i;
                if (m >= 0 && m < 5) {
                    #pragma unroll
                    for (int j = 0; j < 12; ++j)
                        vb[i][j] = fmaf(gk[m], t12[j], vb[i][j]);
                }
            }
        }

        // h-blur (symmetric) + zero outside image (sobel zero-padding)
        float sm6[6][6];
        #pragma unroll
        for (int i = 0; i < 6; ++i) {
            const int hh = mh0 + 4 * orow - 1 + i;
            const float rm = (hh >= 0 && hh < H) ? 1.f : 0.f;
            #pragma unroll
            for (int j = 0; j < 6; ++j) {
                const float s5 = fmaf(gn0, vb[i][1 + j] + vb[i][5 + j],
                                 fmaf(gn1, vb[i][2 + j] + vb[i][4 + j],
                                      gn2 * vb[i][3 + j]));
                const int ww = mw0 + 4 * ocol - 1 + j;
                const float cm = (ww >= 0 && ww < W) ? 1.f : 0.f;
                sm6[i][j] = s5 * rm * cm;
            }
        }

        // sobel + mag + 4x4 pool (4 independent accumulators) + sigmoid^2
        float acc[4] = {0.f, 0.f, 0.f, 0.f};
        #pragma unroll
        for (int i = 0; i < 4; ++i) {
            #pragma unroll
            for (int j = 0; j < 4; ++j) {
                const float a00 = sm6[i][j],     a01 = sm6[i][j + 1],     a02 = sm6[i][j + 2];
                const float a10 = sm6[i + 1][j],                          a12 = sm6[i + 1][j + 2];
                const float a20 = sm6[i + 2][j], a21 = sm6[i + 2][j + 1], a22 = sm6[i + 2][j + 2];
                const float gx = (a02 - a00) + 2.f * (a12 - a10) + (a22 - a20);
                const float gy = (a20 + 2.f * a21 + a22) - (a00 + 2.f * a01 + a02);
                acc[i] += sqrtf(gx * gx + gy * gy + 1e-6f);
            }
        }
        const float down = ((acc[0] + acc[1]) + (acc[2] + acc[3])) * (1.f / 16.f);
        const float x = 5.0f * (down - 0.2f);
        const float sg = 1.f / (1.f + expf(-x));
        const size_t o = ((size_t)b * OH + (th * TOH + orow)) * OW + (tw * TOW + ocol);
        out[o] = sg * sg;
    }
}

extern "C" void kernel_launch(void* const* d_in, const int* in_sizes, int n_in,
                              void* d_out, int out_size, void* d_ws, size_t ws_size,
                              hipStream_t stream) {
    const float* in = (const float*)d_in[0];
    float* out = (float*)d_out;

    // Gaussian 1D coefficients (separable: outer(g,g)/(sum g)^2), exact in double.
    const double g0 = std::exp(-4.0 / 4.5);  // x=2
    const double g1 = std::exp(-1.0 / 4.5);  // x=1
    const double g2 = 1.0;                   // x=0
    const double S = 2.0 * (g0 + g1) + g2;
    const float gn0 = (float)(g0 / S);
    const float gn1 = (float)(g1 / S);
    const float gn2 = (float)(g2 / S);

    hipLaunchKernelGGL(edge_fused, dim3(B * NTH * NTW), dim3(256), 0, stream,
                       in, out, gn0, gn1, gn2);
}

// Round 9
// 33.544 us; speedup vs baseline: 1.8689x; 1.0131x over previous
//
#include <hip/hip_runtime.h>
#include <cmath>

// Problem constants (fixed by setup_inputs)
constexpr int B = 16, C = 3, H = 544, W = 960;
constexpr int OH = 136, OW = 240;
constexpr size_t HW = (size_t)H * W;

constexpr int TOH = 8, TOW = 30, NTH = 17, NTW = 8, MH = 32, MW = 120;
constexpr int GR = 40;     // gray rows: global rows mh0-4 .. mh0+35 (rows 0,39 pad)
constexpr int GS = 132;    // gray row stride (floats)
constexpr int NT = 5;      // tasks per thread: 40 rows x 32 quads = 1280 = 5*256

__global__ __launch_bounds__(256, 2)
void edge_fused(const float* __restrict__ in, float* __restrict__ out,
                float gn0, float gn1, float gn2)
{
    __shared__ float gray[GR * GS];   // 21120 B

    const int tid = threadIdx.x;
    const int blk = blockIdx.x;
    const int tw = blk % NTW;
    const int th = (blk / NTW) % NTH;
    const int b  = blk / (NTW * NTH);
    const int mh0 = th * MH, mw0 = tw * MW;
    const float* inb = in + (size_t)b * C * HW;

    // ---- phase A: load unique RGB region once (batched, unconditional),
    //      convert to gray in LDS. gray[r][lc] <-> global (mh0-4+r, mw0-4+lc).
    float4 Rv[NT], Gv[NT], Bv[NT];
    #pragma unroll
    for (int k = 0; k < NT; ++k) {
        const int idx = tid + 256 * k;
        const int r = idx >> 5;          // /32 quads per row
        const int c = idx & 31;
        int g = mh0 - 4 + r;             // row reflect (always valid)
        g = g < 0 ? -g : (g >= H ? 2 * H - 2 - g : g);
        int gcb = mw0 - 4 + 4 * c;       // col clamp keeps alignment; edge quads fixed below
        gcb = gcb < 0 ? 0 : (gcb > W - 4 ? W - 4 : gcb);
        const float* p = inb + (size_t)g * W + gcb;
        Rv[k] = *reinterpret_cast<const float4*>(p);
        Gv[k] = *reinterpret_cast<const float4*>(p + HW);
        Bv[k] = *reinterpret_cast<const float4*>(p + 2 * HW);
    }
    #pragma unroll
    for (int k = 0; k < NT; ++k) {
        const int idx = tid + 256 * k;
        const int r = idx >> 5;
        const int c = idx & 31;
        float4 g;
        g.x = fmaf(0.2989f, Rv[k].x, fmaf(0.587f, Gv[k].x, 0.114f * Bv[k].x));
        g.y = fmaf(0.2989f, Rv[k].y, fmaf(0.587f, Gv[k].y, 0.114f * Bv[k].y));
        g.z = fmaf(0.2989f, Rv[k].z, fmaf(0.587f, Gv[k].z, 0.114f * Bv[k].z));
        g.w = fmaf(0.2989f, Rv[k].w, fmaf(0.587f, Gv[k].w, 0.114f * Bv[k].w));
        const bool edgeq = (tw == 0 && c == 0) || (tw == NTW - 1 && c == 31);
        if (!edgeq)
            *reinterpret_cast<float4*>(&gray[r * GS + 4 * c]) = g;
    }
    // column-reflect fixup for the 40 edge quads (only writer of those quads)
    if ((tw == 0 || tw == NTW - 1) && tid < GR) {
        const int r = tid;
        const int c = (tw == 0) ? 0 : 31;
        int g = mh0 - 4 + r;
        g = g < 0 ? -g : (g >= H ? 2 * H - 2 - g : g);
        float4 gv;
        float* gp = &gv.x;
        #pragma unroll
        for (int m = 0; m < 4; ++m) {
            int gc = mw0 - 4 + 4 * c + m;
            gc = gc < 0 ? -gc : (gc >= W ? 2 * W - 2 - gc : gc);
            const float* p = inb + (size_t)g * W + gc;
            gp[m] = 0.2989f * p[0] + 0.587f * p[HW] + 0.114f * p[2 * HW];
        }
        *reinterpret_cast<float4*>(&gray[r * GS + 4 * c]) = gv;
    }
    __syncthreads();

    // ---- phase B: per LDS row h-blur (12->6), v-accumulate into sm6, then
    //      sobel + pool + sigmoid. Low register footprint (no vb[6][12]). ----
    if (tid < TOH * TOW) {
        const int orow = tid / TOW;
        const int ocol = tid - orow * TOW;
        const int lc0 = 4 * ocol;        // gray local col base (reads lc0..lc0+11)
        const int rb = 4 * orow + 1;     // gray local row base (reads rb..rb+9)

        float sm6[6][6];                 // smooth rows i=0..5, cols j=0..5
        #pragma unroll
        for (int i = 0; i < 6; ++i)
            #pragma unroll
            for (int j = 0; j < 6; ++j) sm6[i][j] = 0.f;

        const float gk[5] = {gn0, gn1, gn2, gn1, gn0};
        #pragma unroll
        for (int tr = 0; tr < 10; ++tr) {
            const float* p = &gray[(rb + tr) * GS + lc0];
            const float4 u = *reinterpret_cast<const float4*>(p);
            const float4 v = *reinterpret_cast<const float4*>(p + 4);
            const float4 w = *reinterpret_cast<const float4*>(p + 8);
            const float t12[12] = {u.x, u.y, u.z, u.w, v.x, v.y, v.z, v.w,
                                   w.x, w.y, w.z, w.w};
            float h6[6];                 // h-blurred gray for this row
            #pragma unroll
            for (int j = 0; j < 6; ++j)
                h6[j] = fmaf(gn0, t12[1 + j] + t12[5 + j],
                        fmaf(gn1, t12[2 + j] + t12[4 + j], gn2 * t12[3 + j]));
            #pragma unroll
            for (int i = 0; i < 6; ++i) {
                const int m = tr - i;
                if (m >= 0 && m < 5) {
                    #pragma unroll
                    for (int j = 0; j < 6; ++j)
                        sm6[i][j] = fmaf(gk[m], h6[j], sm6[i][j]);
                }
            }
        }

        // sobel zero-padding: zero smooth outside the image
        #pragma unroll
        for (int i = 0; i < 6; ++i) {
            const int hh = mh0 + 4 * orow - 1 + i;
            const float rm = (hh >= 0 && hh < H) ? 1.f : 0.f;
            #pragma unroll
            for (int j = 0; j < 6; ++j) {
                const int ww = mw0 + 4 * ocol - 1 + j;
                sm6[i][j] *= rm * ((ww >= 0 && ww < W) ? 1.f : 0.f);
            }
        }

        // sobel + mag + 4x4 pool (4 independent accumulators) + sigmoid^2
        float acc[4] = {0.f, 0.f, 0.f, 0.f};
        #pragma unroll
        for (int i = 0; i < 4; ++i) {
            #pragma unroll
            for (int j = 0; j < 4; ++j) {
                const float a00 = sm6[i][j],     a01 = sm6[i][j + 1],     a02 = sm6[i][j + 2];
                const float a10 = sm6[i + 1][j],                          a12 = sm6[i + 1][j + 2];
                const float a20 = sm6[i + 2][j], a21 = sm6[i + 2][j + 1], a22 = sm6[i + 2][j + 2];
                const float gx = (a02 - a00) + 2.f * (a12 - a10) + (a22 - a20);
                const float gy = (a20 + 2.f * a21 + a22) - (a00 + 2.f * a01 + a02);
                acc[i] += sqrtf(gx * gx + gy * gy + 1e-6f);
            }
        }
        const float down = ((acc[0] + acc[1]) + (acc[2] + acc[3])) * (1.f / 16.f);
        const float x = 5.0f * (down - 0.2f);
        const float sg = 1.f / (1.f + __expf(-x));
        const size_t o = ((size_t)b * OH + (th * TOH + orow)) * OW + (tw * TOW + ocol);
        out[o] = sg * sg;
    }
}

extern "C" void kernel_launch(void* const* d_in, const int* in_sizes, int n_in,
                              void* d_out, int out_size, void* d_ws, size_t ws_size,
                              hipStream_t stream) {
    const float* in = (const float*)d_in[0];
    float* out = (float*)d_out;

    // Gaussian 1D coefficients (separable: outer(g,g)/(sum g)^2), exact in double.
    const double g0 = std::exp(-4.0 / 4.5);  // x=2
    const double g1 = std::exp(-1.0 / 4.5);  // x=1
    const double g2 = 1.0;                   // x=0
    const double S = 2.0 * (g0 + g1) + g2;
    const float gn0 = (float)(g0 / S);
    const float gn1 = (float)(g1 / S);
    const float gn2 = (float)(g2 / S);

    hipLaunchKernelGGL(edge_fused, dim3(B * NTH * NTW), dim3(256), 0, stream,
                       in, out, gn0, gn1, gn2);
}